// Round 3
// baseline (1247.216 us; speedup 1.0000x reference)
//
#include <hip/hip_runtime.h>
#include <hip/hip_bf16.h>

// Sizes fixed by the reference problem.
#define NN       800000
#define NODE_HD  128
#define MOLR     256
#define IN_DIM   640
#define H1DIM    256
#define H2DIM    128
#define MTILE    64
#define XS       328   // x_lds row stride in shorts: 320 + 8 pad (656B -> 4-bank skew, 2-way max = free)
#define H1S      264   // h1_lds row stride in shorts: 256 + 8 pad

typedef __attribute__((ext_vector_type(4))) float f32x4;
typedef __attribute__((ext_vector_type(4))) short s16x4;
typedef __attribute__((ext_vector_type(8))) short s16x8;

__device__ __forceinline__ short f2bf(float f) {
    union { float f; unsigned u; } v; v.f = f;
    unsigned r = v.u + 0x7fffu + ((v.u >> 16) & 1u);   // round-to-nearest-even
    return (short)(r >> 16);
}

// Pack W1 [640][256] f32 row-major -> bf16 MFMA B-fragment order.
// t = ((kb*16+nb)*64 + lane)*8 + j ; element = W1[kb*32 + (lane>>4)*8 + j][nb*16 + (lane&15)]
__global__ void pack_w1(const float* __restrict__ W1, short* __restrict__ W1p) {
    int t = blockIdx.x * 256 + threadIdx.x;          // < 640*256
    int j = t & 7, l = (t >> 3) & 63, blk = t >> 9;
    int nb = blk & 15, kb = blk >> 4;
    int k = kb * 32 + (l >> 4) * 8 + j;
    int n = nb * 16 + (l & 15);
    W1p[t] = f2bf(W1[k * H1DIM + n]);
}

// Pack W2 [256][128] -> same fragment order (8 n-blocks).
__global__ void pack_w2(const float* __restrict__ W2, short* __restrict__ W2p) {
    int t = blockIdx.x * 256 + threadIdx.x;          // < 256*128
    int j = t & 7, l = (t >> 3) & 63, blk = t >> 9;
    int nb = blk & 7, kb = blk >> 3;
    int k = kb * 32 + (l >> 4) * 8 + j;
    int n = nb * 16 + (l & 15);
    W2p[t] = f2bf(W2[k * H2DIM + n]);
}

__launch_bounds__(256, 2)
__global__ void mlp_fused(const float* __restrict__ nh,
                          const float* __restrict__ c2,
                          const float* __restrict__ tm,
                          const int*   __restrict__ bidx,
                          const short* __restrict__ W1p,
                          const float* __restrict__ b1,
                          const short* __restrict__ W2p,
                          const float* __restrict__ b2,
                          const float* __restrict__ W3,
                          const float* __restrict__ b3,
                          float* __restrict__ out) {
    __shared__ short x_lds[MTILE * XS];     // 41984 B
    __shared__ short h1_lds[MTILE * H1S];   // 33792 B
    __shared__ float b1_lds[H1DIM];
    __shared__ float b2_lds[H2DIM];
    __shared__ float w3_lds[H2DIM];
    __shared__ int   bi_lds[MTILE];
    __shared__ float part_lds[4][MTILE];

    const int tid  = threadIdx.x;
    const int base = blockIdx.x * MTILE;

    if (tid < MTILE) bi_lds[tid] = bidx[base + tid];
    b1_lds[tid] = b1[tid];                              // 256 threads, 256 biases
    if (tid < H2DIM) { b2_lds[tid] = b2[tid]; w3_lds[tid] = W3[tid]; }
    __syncthreads();

    const int l  = tid & 63;
    const int w  = tid >> 6;       // wave id 0..3
    const int lr = l & 15;         // col-in-16 (C/D) / row-in-16 (A)
    const int lh = l >> 4;         // 0..3

    const f32x4* nh4 = reinterpret_cast<const f32x4*>(nh);
    const f32x4* c24 = reinterpret_cast<const f32x4*>(c2);
    const f32x4* tm4 = reinterpret_cast<const f32x4*>(tm);

    f32x4 acc[4][4] = {};   // layer-1: wave computes 64 rows x 64 cols

    for (int chunk = 0; chunk < 2; ++chunk) {
        // ---- stage 64 x 320 f32 -> bf16 LDS (gather on the fly) ----
        #pragma unroll
        for (int i = 0; i < 20; ++i) {
            int idx = tid + i * 256;          // 0..5119
            int row = idx / 80;               // 80 f32x4 per row-chunk
            int q   = idx - row * 80;
            int gc4 = chunk * 80 + q;         // global float4-col 0..159
            int bi  = bi_lds[row];
            f32x4 v;
            if (gc4 < 32)       v = nh4[(size_t)(base + row) * 32 + gc4];
            else if (gc4 < 96)  v = c24[(size_t)bi * 64 + (gc4 - 32)];
            else                v = tm4[(size_t)bi * 64 + (gc4 - 96)];
            s16x4 sv;
            sv[0] = f2bf(v[0]); sv[1] = f2bf(v[1]); sv[2] = f2bf(v[2]); sv[3] = f2bf(v[3]);
            *reinterpret_cast<s16x4*>(&x_lds[row * XS + q * 4]) = sv;
        }
        __syncthreads();

        // ---- layer-1 MFMA over this K-chunk (10 steps of K=32) ----
        for (int kl = 0; kl < 10; ++kl) {
            const int ks = chunk * 10 + kl;
            s16x8 a[4], bf[4];
            #pragma unroll
            for (int m = 0; m < 4; ++m)
                a[m] = *reinterpret_cast<const s16x8*>(
                          &x_lds[(m * 16 + lr) * XS + kl * 32 + lh * 8]);
            #pragma unroll
            for (int n = 0; n < 4; ++n)
                bf[n] = *reinterpret_cast<const s16x8*>(
                          &W1p[(((ks * 16) + (w * 4 + n)) * 64 + l) * 8]);
            #pragma unroll
            for (int m = 0; m < 4; ++m)
                #pragma unroll
                for (int n = 0; n < 4; ++n)
                    acc[m][n] = __builtin_amdgcn_mfma_f32_16x16x32_bf16(
                                    a[m], bf[n], acc[m][n], 0, 0, 0);
        }
        __syncthreads();   // x_lds free for next chunk
    }

    // ---- h1 = relu(acc + b1) -> bf16 LDS ----
    #pragma unroll
    for (int m = 0; m < 4; ++m)
        #pragma unroll
        for (int n = 0; n < 4; ++n)
            #pragma unroll
            for (int r = 0; r < 4; ++r) {
                int row = m * 16 + lh * 4 + r;        // C/D: row=(lane>>4)*4+reg
                int col = w * 64 + n * 16 + lr;       //      col=lane&15
                float v = acc[m][n][r] + b1_lds[col];
                h1_lds[row * H1S + col] = f2bf(fmaxf(v, 0.f));
            }
    __syncthreads();

    // ---- layer-2: [64][256] @ [256][128], wave computes 64 x 32 cols ----
    f32x4 acc2[4][2] = {};
    for (int ks = 0; ks < 8; ++ks) {
        s16x8 a[4], bf[2];
        #pragma unroll
        for (int m = 0; m < 4; ++m)
            a[m] = *reinterpret_cast<const s16x8*>(
                      &h1_lds[(m * 16 + lr) * H1S + ks * 32 + lh * 8]);
        #pragma unroll
        for (int n = 0; n < 2; ++n)
            bf[n] = *reinterpret_cast<const s16x8*>(
                      &W2p[((ks * 8 + (w * 2 + n)) * 64 + l) * 8]);
        #pragma unroll
        for (int m = 0; m < 4; ++m)
            #pragma unroll
            for (int n = 0; n < 2; ++n)
                acc2[m][n] = __builtin_amdgcn_mfma_f32_16x16x32_bf16(
                                 a[m], bf[n], acc2[m][n], 0, 0, 0);
    }

    // ---- layer-3: relu(acc2+b2) . W3, reduce across the 16 col-lanes ----
    float part[4][4] = {};   // [m][reg] -> row = m*16 + lh*4 + reg
    #pragma unroll
    for (int m = 0; m < 4; ++m)
        #pragma unroll
        for (int n = 0; n < 2; ++n)
            #pragma unroll
            for (int r = 0; r < 4; ++r) {
                int col = w * 32 + n * 16 + lr;
                float v = fmaxf(acc2[m][n][r] + b2_lds[col], 0.f);
                part[m][r] += v * w3_lds[col];
            }
    #pragma unroll
    for (int mask = 1; mask <= 8; mask <<= 1)
        #pragma unroll
        for (int m = 0; m < 4; ++m)
            #pragma unroll
            for (int r = 0; r < 4; ++r)
                part[m][r] += __shfl_xor(part[m][r], mask, 64);
    if (lr == 0)
        #pragma unroll
        for (int m = 0; m < 4; ++m)
            #pragma unroll
            for (int r = 0; r < 4; ++r)
                part_lds[w][m * 16 + lh * 4 + r] = part[m][r];
    __syncthreads();

    if (tid < MTILE) {
        float logit = part_lds[0][tid] + part_lds[1][tid] +
                      part_lds[2][tid] + part_lds[3][tid] + b3[0];
        out[base + tid] = 1.f / (1.f + __expf(-logit));
    }
}

extern "C" void kernel_launch(void* const* d_in, const int* in_sizes, int n_in,
                              void* d_out, int out_size, void* d_ws, size_t ws_size,
                              hipStream_t stream) {
    (void)in_sizes; (void)n_in; (void)out_size; (void)ws_size;
    const float* nh   = (const float*)d_in[0];
    const float* c2   = (const float*)d_in[1];
    const float* tm   = (const float*)d_in[2];
    const int*   bidx = (const int*)  d_in[3];
    const float* W1   = (const float*)d_in[4];
    const float* b1   = (const float*)d_in[5];
    const float* W2   = (const float*)d_in[6];
    const float* b2   = (const float*)d_in[7];
    const float* W3   = (const float*)d_in[8];
    const float* b3   = (const float*)d_in[9];
    float* out = (float*)d_out;

    short* W1p = (short*)d_ws;                 // 640*256 bf16 = 327,680 B
    short* W2p = W1p + IN_DIM * H1DIM;         // 256*128 bf16 =  65,536 B

    pack_w1<<<dim3((IN_DIM * H1DIM) / 256), dim3(256), 0, stream>>>(W1, W1p);
    pack_w2<<<dim3((H1DIM * H2DIM) / 256), dim3(256), 0, stream>>>(W2, W2p);
    mlp_fused<<<dim3(NN / MTILE), dim3(256), 0, stream>>>(
        nh, c2, tm, bidx, W1p, b1, W2p, b2, W3, b3, out);
}